// Round 2
// baseline (4872.300 us; speedup 1.0000x reference)
//
#include <hip/hip_runtime.h>

#define NPn 100000
#define NSn 50000
#define PDk 1024
#define SDk 512
#define EPe 3200000
#define ESe 1600000
#define ELe 2000000
#define NB_P 196   // ceil(100000/512)
#define NB_S 98    // ceil(50000/512)

// ---- bucket histogram: bcnt[b] += #edges with dst>>9 == b ----
__global__ void k_bhist(const int* __restrict__ dst, int E, int* __restrict__ bcnt,
                        int NB) {
  __shared__ int h[256];
  int t = threadIdx.x;
  if (t < NB) h[t] = 0;
  __syncthreads();
  for (int i = blockIdx.x * 256 + t; i < E; i += gridDim.x * 256)
    atomicAdd(&h[dst[i] >> 9], 1);
  __syncthreads();
  if (t < NB && h[t]) atomicAdd(&bcnt[t], h[t]);
}

// ---- tiny scan over buckets (<=256), one block of 256 threads ----
__global__ void k_bscan(const int* __restrict__ bcnt, int* __restrict__ boff,
                        int* __restrict__ bcur, int NB, int E, int* __restrict__ row,
                        int N) {
  __shared__ int wsum[4];
  int t = threadIdx.x, lane = t & 63, w = t >> 6;
  int v = (t < NB) ? bcnt[t] : 0;
  int x = v;
#pragma unroll
  for (int off = 1; off < 64; off <<= 1) {
    int y = __shfl_up(x, off);
    if (lane >= off) x += y;
  }
  if (lane == 63) wsum[w] = x;
  __syncthreads();
  int woff = 0;
  for (int j = 0; j < w; ++j) woff += wsum[j];
  int ex = woff + x - v;
  if (t < NB) { boff[t] = ex; bcur[t] = ex; }
  if (t == 0) { boff[NB] = E; row[N] = E; }
}

// ---- partition edges into buckets, packed (src<<9)|dst_local ----
__global__ void k_bucket(const int* __restrict__ src, const int* __restrict__ dst,
                         int E, int* __restrict__ bcur, int* __restrict__ bdata) {
  for (int i = blockIdx.x * 256 + threadIdx.x; i < E; i += gridDim.x * 256) {
    int d = dst[i];
    int p = atomicAdd(&bcur[d >> 9], 1);
    bdata[p] = (src[i] << 9) | (d & 511);
  }
}

// ---- per-bucket: local hist -> scan -> row/dinv/col ----
__global__ __launch_bounds__(256) void k_build(const int* __restrict__ bdata,
                                               const int* __restrict__ boff,
                                               int* __restrict__ col,
                                               int* __restrict__ row,
                                               float* __restrict__ dinv, int N) {
  __shared__ int hist[512];
  __shared__ int excl[512];
  __shared__ int wsum[4];
  int b = blockIdx.x, t = threadIdx.x;
  int s = boff[b], e = boff[b + 1];
  int n0 = b << 9;
  hist[t] = 0; hist[t + 256] = 0;
  __syncthreads();
  for (int i = s + t; i < e; i += 256) atomicAdd(&hist[bdata[i] & 511], 1);
  __syncthreads();
  // 512-entry exclusive scan with 256 threads (2 elems/thread)
  int a0 = hist[2 * t], a1 = hist[2 * t + 1];
  int ps = a0 + a1;
  int lane = t & 63, w = t >> 6;
  int x = ps;
#pragma unroll
  for (int off = 1; off < 64; off <<= 1) {
    int y = __shfl_up(x, off);
    if (lane >= off) x += y;
  }
  if (lane == 63) wsum[w] = x;
  __syncthreads();
  int woff = 0;
  for (int j = 0; j < w; ++j) woff += wsum[j];
  int ex = woff + x - ps;
  excl[2 * t] = ex;
  excl[2 * t + 1] = ex + a0;
  __syncthreads();
  for (int l = t; l < 512; l += 256) {
    int n = n0 + l;
    if (n < N) {
      row[n] = s + excl[l];
      dinv[n] = rsqrtf((float)(hist[l] + 1));
    }
  }
  __syncthreads();
  // place (excl doubles as cursor)
  for (int i = s + t; i < e; i += 256) {
    int v = bdata[i];
    int p = atomicAdd(&excl[v & 511], 1);
    col[s + p] = v >> 9;
  }
}

// C[M,64] = A[M,K] @ W[K,64], K % 32 == 0. 256 thr, 64x64 tile, 4x4 micro.
__global__ __launch_bounds__(256) void k_gemm64(const float* __restrict__ A,
                                                const float* __restrict__ W,
                                                float* __restrict__ C, int M, int K) {
  __shared__ float as[32][68];
  __shared__ float bs[32][68];
  int tid = threadIdx.x;
  int tx = tid & 15, ty = tid >> 4;
  int row0 = blockIdx.x * 64;
  float acc[4][4] = {};
  for (int k0 = 0; k0 < K; k0 += 32) {
    {
      int r = tid >> 2;
      int kk = (tid & 3) * 8;
      int grow = row0 + r;
      float4 v0 = make_float4(0.f, 0.f, 0.f, 0.f), v1 = v0;
      if (grow < M) {
        const float* srcp = A + (size_t)grow * K + k0 + kk;
        v0 = *(const float4*)(srcp);
        v1 = *(const float4*)(srcp + 4);
      }
      as[kk + 0][r] = v0.x; as[kk + 1][r] = v0.y; as[kk + 2][r] = v0.z; as[kk + 3][r] = v0.w;
      as[kk + 4][r] = v1.x; as[kk + 5][r] = v1.y; as[kk + 6][r] = v1.z; as[kk + 7][r] = v1.w;
    }
    {
      int kk = tid >> 3;
      int n = (tid & 7) * 8;
      const float* srcp = W + (size_t)(k0 + kk) * 64 + n;
      float4 v0 = *(const float4*)(srcp);
      float4 v1 = *(const float4*)(srcp + 4);
      *(float4*)&bs[kk][n] = v0;
      *(float4*)&bs[kk][n + 4] = v1;
    }
    __syncthreads();
#pragma unroll
    for (int kk = 0; kk < 32; ++kk) {
      float4 a = *(const float4*)&as[kk][ty * 4];
      float4 b = *(const float4*)&bs[kk][tx * 4];
      float av[4] = {a.x, a.y, a.z, a.w};
      float bv[4] = {b.x, b.y, b.z, b.w};
#pragma unroll
      for (int i = 0; i < 4; ++i)
#pragma unroll
        for (int j = 0; j < 4; ++j) acc[i][j] += av[i] * bv[j];
    }
    __syncthreads();
  }
  int r0 = row0 + ty * 4, c0 = tx * 4;
#pragma unroll
  for (int i = 0; i < 4; ++i) {
    int r = r0 + i;
    if (r < M)
      *(float4*)&C[(size_t)r * 64 + c0] =
          make_float4(acc[i][0], acc[i][1], acc[i][2], acc[i][3]);
  }
}

// out[i,:] = dinv[i]*( sum_j dinv[j]*h[j,:] + dinv[i]*h[i,:] ) + bias
__global__ void k_agg(const float* __restrict__ h, const int* __restrict__ row,
                      const int* __restrict__ col, const float* __restrict__ dinv,
                      const float* __restrict__ bias, float* __restrict__ out, int N) {
  int w = threadIdx.x >> 6, lane = threadIdx.x & 63;
  int i = blockIdx.x * 4 + w;
  if (i >= N) return;
  float di = dinv[i];
  int s = row[i], e = row[i + 1];
  float acc0 = di * h[(size_t)i * 64 + lane];
  float acc1 = 0.f, acc2 = 0.f, acc3 = 0.f;
  for (int base = s; base < e; base += 64) {
    int idx = base + lane;
    int cidx = (idx < e) ? col[idx] : 0;
    float dv = (idx < e) ? dinv[cidx] : 0.f;
    int cnt = min(64, e - base);
    int t = 0;
    for (; t + 4 <= cnt; t += 4) {
      int j0 = __shfl(cidx, t), j1 = __shfl(cidx, t + 1);
      int j2 = __shfl(cidx, t + 2), j3 = __shfl(cidx, t + 3);
      float d0 = __shfl(dv, t), d1 = __shfl(dv, t + 1);
      float d2 = __shfl(dv, t + 2), d3 = __shfl(dv, t + 3);
      float h0 = h[(size_t)j0 * 64 + lane];
      float h1v = h[(size_t)j1 * 64 + lane];
      float h2 = h[(size_t)j2 * 64 + lane];
      float h3 = h[(size_t)j3 * 64 + lane];
      acc0 += d0 * h0; acc1 += d1 * h1v; acc2 += d2 * h2; acc3 += d3 * h3;
    }
    for (; t < cnt; ++t) {
      int j = __shfl(cidx, t);
      float dj = __shfl(dv, t);
      acc0 += dj * h[(size_t)j * 64 + lane];
    }
  }
  out[(size_t)i * 64 + lane] = di * (acc0 + acc1 + acc2 + acc3) + bias[lane];
}

// fold: M = Wproj[sel]@Wl1 (64x64); W2m = W2@M; c2 = b2@M; cvec = bproj@Wl1 + bl1
__global__ __launch_bounds__(256) void k_fold2(
    const float* __restrict__ Wproj, const float* __restrict__ bproj,
    const float* __restrict__ Wl1, const float* __restrict__ bl1,
    const float* __restrict__ Wp2, const float* __restrict__ bp2,
    const float* __restrict__ Ws2, const float* __restrict__ bs2,
    float* __restrict__ W2m_p, float* __restrict__ c2_p, float* __restrict__ W2m_s,
    float* __restrict__ c2_s, float* __restrict__ cvec) {
  int which = blockIdx.x;
  const float* W2 = which ? Ws2 : Wp2;
  const float* b2v = which ? bs2 : bp2;
  float* W2m = which ? W2m_s : W2m_p;
  float* c2 = which ? c2_s : c2_p;
  __shared__ float M[64][64];
  int t = threadIdx.x;
  for (int idx = t; idx < 4096; idx += 256) {
    int a = idx >> 6, c = idx & 63;
    const float* wr = Wproj + (size_t)(which * 64 + a) * 128;
    float sum = 0.f;
    for (int k = 0; k < 128; ++k) sum += wr[k] * Wl1[(size_t)k * 64 + c];
    M[a][c] = sum;
  }
  __syncthreads();
  for (int idx = t; idx < 4096; idx += 256) {
    int a = idx >> 6, c = idx & 63;
    float sum = 0.f;
    for (int k = 0; k < 64; ++k) sum += W2[a * 64 + k] * M[k][c];
    W2m[idx] = sum;
  }
  if (t < 64) {
    float sum = 0.f;
    for (int k = 0; k < 64; ++k) sum += b2v[k] * M[k][t];
    c2[t] = sum;
  }
  if (which == 0 && t >= 64 && t < 128) {
    int c = t - 64;
    float sum = bl1[c];
    for (int k = 0; k < 128; ++k) sum += bproj[k] * Wl1[(size_t)k * 64 + c];
    cvec[c] = sum;
  }
}

// out[e] = relu(P[ep[e],:] + S[es[e],:] + c) . wl2 + bl2   (16 lanes per edge)
__global__ void k_link(const float* __restrict__ P, const float* __restrict__ S,
                       const int* __restrict__ ep, const int* __restrict__ es,
                       const float* __restrict__ cvec, const float* __restrict__ wl2,
                       const float* __restrict__ bl2, float* __restrict__ out, int EL) {
  int lane = threadIdx.x & 63;
  int g = lane >> 4;
  int f = lane & 15;
  int wave = threadIdx.x >> 6;
  float4 c4 = *(const float4*)&cvec[f * 4];
  float4 w4 = *(const float4*)&wl2[f * 4];
  float b2 = bl2[0];
  int e0 = blockIdx.x * 16 + wave * 4 + g;
  int step = gridDim.x * 16;
  for (int e = e0; e < EL; e += step) {
    int rp = ep[e], rs = es[e];
    float4 p4 = *(const float4*)&P[(size_t)rp * 64 + f * 4];
    float4 s4 = *(const float4*)&S[(size_t)rs * 64 + f * 4];
    float u, acc;
    u = p4.x + s4.x + c4.x; acc  = fmaxf(u, 0.f) * w4.x;
    u = p4.y + s4.y + c4.y; acc += fmaxf(u, 0.f) * w4.y;
    u = p4.z + s4.z + c4.z; acc += fmaxf(u, 0.f) * w4.z;
    u = p4.w + s4.w + c4.w; acc += fmaxf(u, 0.f) * w4.w;
    acc += __shfl_xor(acc, 1);
    acc += __shfl_xor(acc, 2);
    acc += __shfl_xor(acc, 4);
    acc += __shfl_xor(acc, 8);
    if (f == 0) out[e] = acc + b2;
  }
}

extern "C" void kernel_launch(void* const* d_in, const int* in_sizes, int n_in,
                              void* d_out, int out_size, void* d_ws, size_t ws_size,
                              hipStream_t stream) {
  const float* x_p  = (const float*)d_in[0];
  const float* x_s  = (const float*)d_in[1];
  const int*   ei_p = (const int*)d_in[2];
  const int*   ei_s = (const int*)d_in[3];
  const int*   ed_p = (const int*)d_in[4];
  const int*   ed_s = (const int*)d_in[5];
  const float* Wp1 = (const float*)d_in[6];  const float* bp1 = (const float*)d_in[7];
  const float* Ws1 = (const float*)d_in[8];  const float* bs1 = (const float*)d_in[9];
  const float* Wp2 = (const float*)d_in[10]; const float* bp2 = (const float*)d_in[11];
  const float* Ws2 = (const float*)d_in[12]; const float* bs2 = (const float*)d_in[13];
  const float* Wproj = (const float*)d_in[14]; const float* bproj = (const float*)d_in[15];
  const float* Wl1 = (const float*)d_in[16]; const float* bl1 = (const float*)d_in[17];
  const float* Wl2 = (const float*)d_in[18]; const float* bl2 = (const float*)d_in[19];
  float* out = (float*)d_out;

  char* wsp = (char*)d_ws;
  size_t off = 0;
  auto alloc = [&](size_t b) -> void* {
    void* p = wsp + off;
    off = (off + b + 255) & ~(size_t)255;
    return p;
  };
  float* bufA_p = (float*)alloc((size_t)NPn * 64 * 4);
  float* bufB_p = (float*)alloc((size_t)NPn * 64 * 4);
  float* bufA_s = (float*)alloc((size_t)NSn * 64 * 4);
  float* bufB_s = (float*)alloc((size_t)NSn * 64 * 4);
  int*   col_p  = (int*)alloc((size_t)EPe * 4);
  int*   col_s  = (int*)alloc((size_t)ESe * 4);
  float* dinv_p = (float*)alloc((size_t)NPn * 4);
  float* dinv_s = (float*)alloc((size_t)NSn * 4);
  int*   row_p  = (int*)alloc((size_t)(NPn + 1) * 4);
  int*   row_s  = (int*)alloc((size_t)(NSn + 1) * 4);
  int*   bcnt_p = (int*)alloc(256 * 4);
  int*   bcnt_s = (int*)alloc(256 * 4);
  int*   boff_p = (int*)alloc(257 * 4);
  int*   boff_s = (int*)alloc(257 * 4);
  int*   bcur_p = (int*)alloc(256 * 4);
  int*   bcur_s = (int*)alloc(256 * 4);
  float* W2m_p  = (float*)alloc(64 * 64 * 4);
  float* W2m_s  = (float*)alloc(64 * 64 * 4);
  float* c2_p   = (float*)alloc(64 * 4);
  float* c2_s   = (float*)alloc(64 * 4);
  float* cvec   = (float*)alloc(64 * 4);
  (void)ws_size; (void)n_in; (void)in_sizes; (void)out_size;

  // bdata aliases bufA (only used before the GEMMs touch bufA; stream is serial)
  int* bdata_p = (int*)bufA_p;
  int* bdata_s = (int*)bufA_s;

  const int* src_p = ei_p;           const int* dst_p = ei_p + EPe;
  const int* src_s = ei_s;           const int* dst_s = ei_s + ESe;

  hipMemsetAsync(bcnt_p, 0, 256 * 4, stream);
  hipMemsetAsync(bcnt_s, 0, 256 * 4, stream);

  // weight folding (independent)
  k_fold2<<<2, 256, 0, stream>>>(Wproj, bproj, Wl1, bl1, Wp2, bp2, Ws2, bs2,
                                 W2m_p, c2_p, W2m_s, c2_s, cvec);

  // bucket counting-sort CSR build
  k_bhist<<<1280, 256, 0, stream>>>(dst_p, EPe, bcnt_p, NB_P);
  k_bhist<<<1280, 256, 0, stream>>>(dst_s, ESe, bcnt_s, NB_S);
  k_bscan<<<1, 256, 0, stream>>>(bcnt_p, boff_p, bcur_p, NB_P, EPe, row_p, NPn);
  k_bscan<<<1, 256, 0, stream>>>(bcnt_s, boff_s, bcur_s, NB_S, ESe, row_s, NSn);
  k_bucket<<<1280, 256, 0, stream>>>(src_p, dst_p, EPe, bcur_p, bdata_p);
  k_bucket<<<1280, 256, 0, stream>>>(src_s, dst_s, ESe, bcur_s, bdata_s);
  k_build<<<NB_P, 256, 0, stream>>>(bdata_p, boff_p, col_p, row_p, dinv_p, NPn);
  k_build<<<NB_S, 256, 0, stream>>>(bdata_s, boff_s, col_s, row_s, dinv_s, NSn);

  // protein: t = x@W1 ; h1 = Agg(t)+b1 ; t = h1@W2m ; P = Agg(t)+c2
  k_gemm64<<<(NPn + 63) / 64, 256, 0, stream>>>(x_p, Wp1, bufA_p, NPn, PDk);
  k_agg<<<(NPn + 3) / 4, 256, 0, stream>>>(bufA_p, row_p, col_p, dinv_p, bp1, bufB_p, NPn);
  k_gemm64<<<(NPn + 63) / 64, 256, 0, stream>>>(bufB_p, W2m_p, bufA_p, NPn, 64);
  k_agg<<<(NPn + 3) / 4, 256, 0, stream>>>(bufA_p, row_p, col_p, dinv_p, c2_p, bufB_p, NPn);

  // substrate
  k_gemm64<<<(NSn + 63) / 64, 256, 0, stream>>>(x_s, Ws1, bufA_s, NSn, SDk);
  k_agg<<<(NSn + 3) / 4, 256, 0, stream>>>(bufA_s, row_s, col_s, dinv_s, bs1, bufB_s, NSn);
  k_gemm64<<<(NSn + 63) / 64, 256, 0, stream>>>(bufB_s, W2m_s, bufA_s, NSn, 64);
  k_agg<<<(NSn + 3) / 4, 256, 0, stream>>>(bufA_s, row_s, col_s, dinv_s, c2_s, bufB_s, NSn);

  // link predictor
  k_link<<<(ELe + 15) / 16, 256, 0, stream>>>(bufB_p, bufB_s, ed_p, ed_s, cvec, Wl2,
                                              bl2, out, ELe);
}

// Round 3
// 1589.288 us; speedup vs baseline: 3.0657x; 3.0657x over previous
//
#include <hip/hip_runtime.h>

#define NPn 100000
#define NSn 50000
#define PDk 1024
#define SDk 512
#define EPe 3200000
#define ESe 1600000
#define ELe 2000000
#define NB_P 196   // ceil(100000/512)
#define NB_S 98    // ceil(50000/512)
#define CHUNK 8192

// ---- bucket histogram: bcnt[b] += #edges with dst>>9 == b ----
__global__ void k_bhist(const int* __restrict__ dst, int E, int* __restrict__ bcnt,
                        int NB) {
  __shared__ int h[256];
  int t = threadIdx.x;
  if (t < NB) h[t] = 0;
  __syncthreads();
  for (int i = blockIdx.x * 256 + t; i < E; i += gridDim.x * 256)
    atomicAdd(&h[dst[i] >> 9], 1);
  __syncthreads();
  if (t < NB && h[t]) atomicAdd(&bcnt[t], h[t]);
}

// ---- tiny scan over buckets (<=256), one block of 256 threads ----
__global__ void k_bscan(const int* __restrict__ bcnt, int* __restrict__ boff,
                        int* __restrict__ bcur, int NB, int E, int* __restrict__ row,
                        int N) {
  __shared__ int wsum[4];
  int t = threadIdx.x, lane = t & 63, w = t >> 6;
  int v = (t < NB) ? bcnt[t] : 0;
  int x = v;
#pragma unroll
  for (int off = 1; off < 64; off <<= 1) {
    int y = __shfl_up(x, off);
    if (lane >= off) x += y;
  }
  if (lane == 63) wsum[w] = x;
  __syncthreads();
  int woff = 0;
  for (int j = 0; j < w; ++j) woff += wsum[j];
  int ex = woff + x - v;
  if (t < NB) { boff[t] = ex; bcur[t] = ex; }
  if (t == 0) { boff[NB] = E; row[N] = E; }
}

// ---- blocked partition: per-block LDS hist -> one global reserve per bucket ->
//      LDS staging grouped by bucket -> coalesced windowed writes ----
__global__ __launch_bounds__(256) void k_bucket2(const int* __restrict__ src,
                                                 const int* __restrict__ dst, int E,
                                                 int* __restrict__ bcur,
                                                 int* __restrict__ bdata, int NB) {
  __shared__ int hist[256];
  __shared__ int lofs[256];
  __shared__ int delta[256];
  __shared__ int lcur[256];
  __shared__ int wsum[4];
  __shared__ int stage[CHUNK];
  int t = threadIdx.x;
  int base = blockIdx.x * CHUNK;
  int cnt = min(CHUNK, E - base);
  hist[t] = 0;
  __syncthreads();
  for (int i = t; i < cnt; i += 256) atomicAdd(&hist[dst[base + i] >> 9], 1);
  __syncthreads();
  // exclusive scan of hist[0..255]
  int v = hist[t];
  int lane = t & 63, w = t >> 6;
  int x = v;
#pragma unroll
  for (int off = 1; off < 64; off <<= 1) {
    int y = __shfl_up(x, off);
    if (lane >= off) x += y;
  }
  if (lane == 63) wsum[w] = x;
  __syncthreads();
  int woff = 0;
  for (int j = 0; j < w; ++j) woff += wsum[j];
  int ex = woff + x - v;
  lofs[t] = ex;
  lcur[t] = ex;
  if (t < NB) delta[t] = atomicAdd(&bcur[t], v) - ex;  // global window base - local base
  __syncthreads();
  // local placement into stage, grouped by bucket
  for (int i = t; i < cnt; i += 256) {
    int d = dst[base + i];
    int b = d >> 9;
    int p = atomicAdd(&lcur[b], 1);
    stage[p] = (src[base + i] << 9) | (d & 511);
  }
  __syncthreads();
  // stream out: consecutive slots -> consecutive global addrs within a segment
  for (int i = t; i < cnt; i += 256) {
    int lo = 0, hi = NB;  // largest b with lofs[b] <= i
    while (hi - lo > 1) {
      int mid = (lo + hi) >> 1;
      if (lofs[mid] <= i) lo = mid; else hi = mid;
    }
    bdata[delta[lo] + i] = stage[i];
  }
}

// ---- per-bucket: local hist -> scan -> row/dinv/col ----
__global__ __launch_bounds__(256) void k_build(const int* __restrict__ bdata,
                                               const int* __restrict__ boff,
                                               int* __restrict__ col,
                                               int* __restrict__ row,
                                               float* __restrict__ dinv, int N) {
  __shared__ int hist[512];
  __shared__ int excl[512];
  __shared__ int wsum[4];
  int b = blockIdx.x, t = threadIdx.x;
  int s = boff[b], e = boff[b + 1];
  int n0 = b << 9;
  hist[t] = 0; hist[t + 256] = 0;
  __syncthreads();
  for (int i = s + t; i < e; i += 256) atomicAdd(&hist[bdata[i] & 511], 1);
  __syncthreads();
  int a0 = hist[2 * t], a1 = hist[2 * t + 1];
  int ps = a0 + a1;
  int lane = t & 63, w = t >> 6;
  int x = ps;
#pragma unroll
  for (int off = 1; off < 64; off <<= 1) {
    int y = __shfl_up(x, off);
    if (lane >= off) x += y;
  }
  if (lane == 63) wsum[w] = x;
  __syncthreads();
  int woff = 0;
  for (int j = 0; j < w; ++j) woff += wsum[j];
  int ex = woff + x - ps;
  excl[2 * t] = ex;
  excl[2 * t + 1] = ex + a0;
  __syncthreads();
  for (int l = t; l < 512; l += 256) {
    int n = n0 + l;
    if (n < N) {
      row[n] = s + excl[l];
      dinv[n] = rsqrtf((float)(hist[l] + 1));
    }
  }
  __syncthreads();
  for (int i = s + t; i < e; i += 256) {
    int v = bdata[i];
    int p = atomicAdd(&excl[v & 511], 1);
    col[s + p] = v >> 9;
  }
}

// C[M,64] = A[M,K] @ W[K,64], K % 32 == 0. 256 thr, 64x64 tile, 4x4 micro.
__global__ __launch_bounds__(256) void k_gemm64(const float* __restrict__ A,
                                                const float* __restrict__ W,
                                                float* __restrict__ C, int M, int K) {
  __shared__ float as[32][68];
  __shared__ float bs[32][68];
  int tid = threadIdx.x;
  int tx = tid & 15, ty = tid >> 4;
  int row0 = blockIdx.x * 64;
  float acc[4][4] = {};
  for (int k0 = 0; k0 < K; k0 += 32) {
    {
      int r = tid >> 2;
      int kk = (tid & 3) * 8;
      int grow = row0 + r;
      float4 v0 = make_float4(0.f, 0.f, 0.f, 0.f), v1 = v0;
      if (grow < M) {
        const float* srcp = A + (size_t)grow * K + k0 + kk;
        v0 = *(const float4*)(srcp);
        v1 = *(const float4*)(srcp + 4);
      }
      as[kk + 0][r] = v0.x; as[kk + 1][r] = v0.y; as[kk + 2][r] = v0.z; as[kk + 3][r] = v0.w;
      as[kk + 4][r] = v1.x; as[kk + 5][r] = v1.y; as[kk + 6][r] = v1.z; as[kk + 7][r] = v1.w;
    }
    {
      int kk = tid >> 3;
      int n = (tid & 7) * 8;
      const float* srcp = W + (size_t)(k0 + kk) * 64 + n;
      float4 v0 = *(const float4*)(srcp);
      float4 v1 = *(const float4*)(srcp + 4);
      *(float4*)&bs[kk][n] = v0;
      *(float4*)&bs[kk][n + 4] = v1;
    }
    __syncthreads();
#pragma unroll
    for (int kk = 0; kk < 32; ++kk) {
      float4 a = *(const float4*)&as[kk][ty * 4];
      float4 b = *(const float4*)&bs[kk][tx * 4];
      float av[4] = {a.x, a.y, a.z, a.w};
      float bv[4] = {b.x, b.y, b.z, b.w};
#pragma unroll
      for (int i = 0; i < 4; ++i)
#pragma unroll
        for (int j = 0; j < 4; ++j) acc[i][j] += av[i] * bv[j];
    }
    __syncthreads();
  }
  int r0 = row0 + ty * 4, c0 = tx * 4;
#pragma unroll
  for (int i = 0; i < 4; ++i) {
    int r = r0 + i;
    if (r < M)
      *(float4*)&C[(size_t)r * 64 + c0] =
          make_float4(acc[i][0], acc[i][1], acc[i][2], acc[i][3]);
  }
}

// out[i,:] = dinv[i]*( sum_j dinv[j]*h[j,:] + dinv[i]*h[i,:] ) + bias
__global__ void k_agg(const float* __restrict__ h, const int* __restrict__ row,
                      const int* __restrict__ col, const float* __restrict__ dinv,
                      const float* __restrict__ bias, float* __restrict__ out, int N) {
  int w = threadIdx.x >> 6, lane = threadIdx.x & 63;
  int i = blockIdx.x * 4 + w;
  if (i >= N) return;
  float di = dinv[i];
  int s = row[i], e = row[i + 1];
  float acc0 = di * h[(size_t)i * 64 + lane];
  float acc1 = 0.f, acc2 = 0.f, acc3 = 0.f;
  for (int base = s; base < e; base += 64) {
    int idx = base + lane;
    int cidx = (idx < e) ? col[idx] : 0;
    float dv = (idx < e) ? dinv[cidx] : 0.f;
    int cnt = min(64, e - base);
    int t = 0;
    for (; t + 4 <= cnt; t += 4) {
      int j0 = __shfl(cidx, t), j1 = __shfl(cidx, t + 1);
      int j2 = __shfl(cidx, t + 2), j3 = __shfl(cidx, t + 3);
      float d0 = __shfl(dv, t), d1 = __shfl(dv, t + 1);
      float d2 = __shfl(dv, t + 2), d3 = __shfl(dv, t + 3);
      float h0 = h[(size_t)j0 * 64 + lane];
      float h1v = h[(size_t)j1 * 64 + lane];
      float h2 = h[(size_t)j2 * 64 + lane];
      float h3 = h[(size_t)j3 * 64 + lane];
      acc0 += d0 * h0; acc1 += d1 * h1v; acc2 += d2 * h2; acc3 += d3 * h3;
    }
    for (; t < cnt; ++t) {
      int j = __shfl(cidx, t);
      float dj = __shfl(dv, t);
      acc0 += dj * h[(size_t)j * 64 + lane];
    }
  }
  out[(size_t)i * 64 + lane] = di * (acc0 + acc1 + acc2 + acc3) + bias[lane];
}

// fold: M = Wproj[sel]@Wl1 (64x64); W2m = W2@M; c2 = b2@M; cvec = bproj@Wl1 + bl1
__global__ __launch_bounds__(256) void k_fold2(
    const float* __restrict__ Wproj, const float* __restrict__ bproj,
    const float* __restrict__ Wl1, const float* __restrict__ bl1,
    const float* __restrict__ Wp2, const float* __restrict__ bp2,
    const float* __restrict__ Ws2, const float* __restrict__ bs2,
    float* __restrict__ W2m_p, float* __restrict__ c2_p, float* __restrict__ W2m_s,
    float* __restrict__ c2_s, float* __restrict__ cvec) {
  int which = blockIdx.x;
  const float* W2 = which ? Ws2 : Wp2;
  const float* b2v = which ? bs2 : bp2;
  float* W2m = which ? W2m_s : W2m_p;
  float* c2 = which ? c2_s : c2_p;
  __shared__ float M[64][64];
  int t = threadIdx.x;
  for (int idx = t; idx < 4096; idx += 256) {
    int a = idx >> 6, c = idx & 63;
    const float* wr = Wproj + (size_t)(which * 64 + a) * 128;
    float sum = 0.f;
    for (int k = 0; k < 128; ++k) sum += wr[k] * Wl1[(size_t)k * 64 + c];
    M[a][c] = sum;
  }
  __syncthreads();
  for (int idx = t; idx < 4096; idx += 256) {
    int a = idx >> 6, c = idx & 63;
    float sum = 0.f;
    for (int k = 0; k < 64; ++k) sum += W2[a * 64 + k] * M[k][c];
    W2m[idx] = sum;
  }
  if (t < 64) {
    float sum = 0.f;
    for (int k = 0; k < 64; ++k) sum += b2v[k] * M[k][t];
    c2[t] = sum;
  }
  if (which == 0 && t >= 64 && t < 128) {
    int c = t - 64;
    float sum = bl1[c];
    for (int k = 0; k < 128; ++k) sum += bproj[k] * Wl1[(size_t)k * 64 + c];
    cvec[c] = sum;
  }
}

// out[e] = relu(P[ep[e],:] + S[es[e],:] + c) . wl2 + bl2   (16 lanes per edge)
__global__ void k_link(const float* __restrict__ P, const float* __restrict__ S,
                       const int* __restrict__ ep, const int* __restrict__ es,
                       const float* __restrict__ cvec, const float* __restrict__ wl2,
                       const float* __restrict__ bl2, float* __restrict__ out, int EL) {
  int lane = threadIdx.x & 63;
  int g = lane >> 4;
  int f = lane & 15;
  int wave = threadIdx.x >> 6;
  float4 c4 = *(const float4*)&cvec[f * 4];
  float4 w4 = *(const float4*)&wl2[f * 4];
  float b2 = bl2[0];
  int e0 = blockIdx.x * 16 + wave * 4 + g;
  int step = gridDim.x * 16;
  for (int e = e0; e < EL; e += step) {
    int rp = ep[e], rs = es[e];
    float4 p4 = *(const float4*)&P[(size_t)rp * 64 + f * 4];
    float4 s4 = *(const float4*)&S[(size_t)rs * 64 + f * 4];
    float u, acc;
    u = p4.x + s4.x + c4.x; acc  = fmaxf(u, 0.f) * w4.x;
    u = p4.y + s4.y + c4.y; acc += fmaxf(u, 0.f) * w4.y;
    u = p4.z + s4.z + c4.z; acc += fmaxf(u, 0.f) * w4.z;
    u = p4.w + s4.w + c4.w; acc += fmaxf(u, 0.f) * w4.w;
    acc += __shfl_xor(acc, 1);
    acc += __shfl_xor(acc, 2);
    acc += __shfl_xor(acc, 4);
    acc += __shfl_xor(acc, 8);
    if (f == 0) out[e] = acc + b2;
  }
}

extern "C" void kernel_launch(void* const* d_in, const int* in_sizes, int n_in,
                              void* d_out, int out_size, void* d_ws, size_t ws_size,
                              hipStream_t stream) {
  const float* x_p  = (const float*)d_in[0];
  const float* x_s  = (const float*)d_in[1];
  const int*   ei_p = (const int*)d_in[2];
  const int*   ei_s = (const int*)d_in[3];
  const int*   ed_p = (const int*)d_in[4];
  const int*   ed_s = (const int*)d_in[5];
  const float* Wp1 = (const float*)d_in[6];  const float* bp1 = (const float*)d_in[7];
  const float* Ws1 = (const float*)d_in[8];  const float* bs1 = (const float*)d_in[9];
  const float* Wp2 = (const float*)d_in[10]; const float* bp2 = (const float*)d_in[11];
  const float* Ws2 = (const float*)d_in[12]; const float* bs2 = (const float*)d_in[13];
  const float* Wproj = (const float*)d_in[14]; const float* bproj = (const float*)d_in[15];
  const float* Wl1 = (const float*)d_in[16]; const float* bl1 = (const float*)d_in[17];
  const float* Wl2 = (const float*)d_in[18]; const float* bl2 = (const float*)d_in[19];
  float* out = (float*)d_out;

  char* wsp = (char*)d_ws;
  size_t off = 0;
  auto alloc = [&](size_t b) -> void* {
    void* p = wsp + off;
    off = (off + b + 255) & ~(size_t)255;
    return p;
  };
  float* bufA_p = (float*)alloc((size_t)NPn * 64 * 4);
  float* bufB_p = (float*)alloc((size_t)NPn * 64 * 4);
  float* bufA_s = (float*)alloc((size_t)NSn * 64 * 4);
  float* bufB_s = (float*)alloc((size_t)NSn * 64 * 4);
  int*   col_p  = (int*)alloc((size_t)EPe * 4);
  int*   col_s  = (int*)alloc((size_t)ESe * 4);
  float* dinv_p = (float*)alloc((size_t)NPn * 4);
  float* dinv_s = (float*)alloc((size_t)NSn * 4);
  int*   row_p  = (int*)alloc((size_t)(NPn + 1) * 4);
  int*   row_s  = (int*)alloc((size_t)(NSn + 1) * 4);
  int*   bcnt_p = (int*)alloc(256 * 4);
  int*   bcnt_s = (int*)alloc(256 * 4);
  int*   boff_p = (int*)alloc(257 * 4);
  int*   boff_s = (int*)alloc(257 * 4);
  int*   bcur_p = (int*)alloc(256 * 4);
  int*   bcur_s = (int*)alloc(256 * 4);
  float* W2m_p  = (float*)alloc(64 * 64 * 4);
  float* W2m_s  = (float*)alloc(64 * 64 * 4);
  float* c2_p   = (float*)alloc(64 * 4);
  float* c2_s   = (float*)alloc(64 * 4);
  float* cvec   = (float*)alloc(64 * 4);
  (void)ws_size; (void)n_in; (void)in_sizes; (void)out_size;

  // bdata aliases bufA (only used before the GEMMs touch bufA; stream is serial)
  int* bdata_p = (int*)bufA_p;
  int* bdata_s = (int*)bufA_s;

  const int* src_p = ei_p;           const int* dst_p = ei_p + EPe;
  const int* src_s = ei_s;           const int* dst_s = ei_s + ESe;

  hipMemsetAsync(bcnt_p, 0, 256 * 4, stream);
  hipMemsetAsync(bcnt_s, 0, 256 * 4, stream);

  // weight folding (independent)
  k_fold2<<<2, 256, 0, stream>>>(Wproj, bproj, Wl1, bl1, Wp2, bp2, Ws2, bs2,
                                 W2m_p, c2_p, W2m_s, c2_s, cvec);

  // bucket counting-sort CSR build
  k_bhist<<<1280, 256, 0, stream>>>(dst_p, EPe, bcnt_p, NB_P);
  k_bhist<<<1280, 256, 0, stream>>>(dst_s, ESe, bcnt_s, NB_S);
  k_bscan<<<1, 256, 0, stream>>>(bcnt_p, boff_p, bcur_p, NB_P, EPe, row_p, NPn);
  k_bscan<<<1, 256, 0, stream>>>(bcnt_s, boff_s, bcur_s, NB_S, ESe, row_s, NSn);
  k_bucket2<<<(EPe + CHUNK - 1) / CHUNK, 256, 0, stream>>>(src_p, dst_p, EPe, bcur_p,
                                                           bdata_p, NB_P);
  k_bucket2<<<(ESe + CHUNK - 1) / CHUNK, 256, 0, stream>>>(src_s, dst_s, ESe, bcur_s,
                                                           bdata_s, NB_S);
  k_build<<<NB_P, 256, 0, stream>>>(bdata_p, boff_p, col_p, row_p, dinv_p, NPn);
  k_build<<<NB_S, 256, 0, stream>>>(bdata_s, boff_s, col_s, row_s, dinv_s, NSn);

  // protein: t = x@W1 ; h1 = Agg(t)+b1 ; t = h1@W2m ; P = Agg(t)+c2
  k_gemm64<<<(NPn + 63) / 64, 256, 0, stream>>>(x_p, Wp1, bufA_p, NPn, PDk);
  k_agg<<<(NPn + 3) / 4, 256, 0, stream>>>(bufA_p, row_p, col_p, dinv_p, bp1, bufB_p, NPn);
  k_gemm64<<<(NPn + 63) / 64, 256, 0, stream>>>(bufB_p, W2m_p, bufA_p, NPn, 64);
  k_agg<<<(NPn + 3) / 4, 256, 0, stream>>>(bufA_p, row_p, col_p, dinv_p, c2_p, bufB_p, NPn);

  // substrate
  k_gemm64<<<(NSn + 63) / 64, 256, 0, stream>>>(x_s, Ws1, bufA_s, NSn, SDk);
  k_agg<<<(NSn + 3) / 4, 256, 0, stream>>>(bufA_s, row_s, col_s, dinv_s, bs1, bufB_s, NSn);
  k_gemm64<<<(NSn + 63) / 64, 256, 0, stream>>>(bufB_s, W2m_s, bufA_s, NSn, 64);
  k_agg<<<(NSn + 3) / 4, 256, 0, stream>>>(bufA_s, row_s, col_s, dinv_s, c2_s, bufB_s, NSn);

  // link predictor
  k_link<<<(ELe + 15) / 16, 256, 0, stream>>>(bufB_p, bufB_s, ed_p, ed_s, cvec, Wl2,
                                              bl2, out, ELe);
}